// Round 5
// baseline (1606.651 us; speedup 1.0000x reference)
//
#include <hip/hip_runtime.h>
#include <cstdint>
#include <cstddef>

typedef unsigned short ushort_t;
typedef __bf16 bf16x8 __attribute__((ext_vector_type(8)));
typedef float floatx4 __attribute__((ext_vector_type(4)));

#define DEV static __device__ __forceinline__

DEV ushort_t f2bf(float f){
  union { float f; uint32_t u; } v; v.f = f;
  uint32_t u = v.u;
  return (ushort_t)((u + 0x7fffu + ((u >> 16) & 1u)) >> 16);
}
DEV float bf2f(ushort_t h){
  union { uint32_t u; float f; } v; v.u = ((uint32_t)h) << 16; return v.f;
}
DEV float sigmoidf_(float x){ return 1.f / (1.f + __expf(-x)); }

#define AS1 __attribute__((address_space(1)))
#define AS3 __attribute__((address_space(3)))
DEV void gld_lds16(const void* g, void* l){
  __builtin_amdgcn_global_load_lds((const AS1 void*)g, (AS3 void*)l, 16, 0, 0);
}

// XCD-locality swizzle: all x-tiles (n) of one y-tile (m) land on the same XCD.
DEV void swz_xy(int& nx, int& my){
  int gx = gridDim.x, gy = gridDim.y;
  int lin = blockIdx.x + gx * blockIdx.y;
  int full = gy & ~7;
  int region = full * gx;
  if (lin < region){ int q = lin >> 3; nx = q % gx; my = (q / gx) * 8 + (lin & 7); }
  else { int r = lin - region; nx = r % gx; my = full + r / gx; }
}

// ---------------- problem constants ----------------
#define BN 2048
#define LD 100
#define DIM 128
#define L1 97   // after k=4
#define L2 92   // after k=6
#define L3 85   // after k=8
#define CC 512  // C = CONV*4

// ---------------- prep: weight transforms + casts ----------------
struct PrepArgs {
  const float *dw1,*dw2,*dw3,*Wda,*Wfa,*Watt,*W1,*W2,*W3,*fw1,*fw2,*fw3;
  ushort_t *bt1,*bt2,*bt3,*bWda,*bWfa,*bWatt,*bW1,*bW2,*bW3;
  float *fw1m,*fw2m,*fw3m;
};

__global__ void prep_k(PrepArgs a){
  int t0 = blockIdx.x * blockDim.x + threadIdx.x;
  int stride = gridDim.x * blockDim.x;
  switch (blockIdx.y){
  case 0:
    for (int i=t0;i<128*512;i+=stride){ int o=i>>9, rem=i&511, kk=rem>>7, c=rem&127;
      a.bt1[i]=f2bf(a.dw1[o*512 + c*4 + kk]); } break;
  case 1:
    for (int i=t0;i<256*768;i+=stride){ int o=i/768, rem=i-o*768, kk=rem>>7, c=rem&127;
      a.bt2[i]=f2bf(a.dw2[o*768 + c*6 + kk]); } break;
  case 2:
    for (int i=t0;i<512*2048;i+=stride){ int o=i>>11, rem=i&2047, kk=rem>>8, c=rem&255;
      a.bt3[i]=f2bf(a.dw3[o*2048 + c*8 + kk]); } break;
  case 3: for (int i=t0;i<262144;i+=stride) a.bWda[i]=f2bf(a.Wda[i]); break;
  case 4: for (int i=t0;i<262144;i+=stride) a.bWfa[i]=f2bf(a.Wfa[i]); break;
  case 5: for (int i=t0;i<262144;i+=stride) a.bWatt[i]=f2bf(a.Watt[i]); break;
  case 6: for (int i=t0;i<1048576;i+=stride) a.bW1[i]=f2bf(a.W1[i]); break;
  case 7: for (int i=t0;i<1048576;i+=stride) a.bW2[i]=f2bf(a.W2[i]); break;
  case 8: for (int i=t0;i<524288;i+=stride) a.bW3[i]=f2bf(a.W3[i]); break;
  case 9:  for (int i=t0;i<7*128;i+=stride){ int ii=i>>7, o=i&127; a.fw1m[i]=a.fw1[o*21 + ii*3 + 1]; } break;
  case 10: for (int i=t0;i<128*256;i+=stride){ int ii=i>>8, o=i&255; a.fw2m[i]=a.fw2[o*384 + ii*3 + 1]; } break;
  case 11: for (int i=t0;i<256*512;i+=stride){ int ii=i>>9, o=i&511; a.fw3m[i]=a.fw3[o*768 + ii*3 + 1]; } break;
  }
}

// ---------------- embedding gather -> bf16 ----------------
__global__ void gather_k(const int* __restrict__ drug, const float* __restrict__ emb,
                         ushort_t* __restrict__ x, int total){
  int g = blockIdx.x * blockDim.x + threadIdx.x;
  if (g >= total) return;
  int c8 = g & 15; int t = g >> 4;
  int tok = drug[t];
  const float* src = emb + (size_t)tok*DIM + c8*8;
  ushort_t* dst = x + ((size_t)t*DIM + c8*8);
  #pragma unroll
  for (int k=0;k<8;k++) dst[k] = f2bf(src[k]);
}

// ---------------- feature NN ----------------
__global__ void featnn_k(const float* __restrict__ feature,
                         const float* __restrict__ fw1m, const float* __restrict__ fb1,
                         const float* __restrict__ fw2m, const float* __restrict__ fb2,
                         const float* __restrict__ fw3m, const float* __restrict__ fb3,
                         float* __restrict__ fnnf, ushort_t* __restrict__ fnnb)
{
  __shared__ float fs[8][7];
  __shared__ float h1s[8][128];
  __shared__ float h2s[8][256];
  int b0 = blockIdx.x * 8;
  int tid = threadIdx.x;
  if (tid < 56){ int bb = tid/7, i = tid - bb*7; fs[bb][i] = feature[(b0+bb)*7 + i]; }
  __syncthreads();
  if (tid < 128){
    float acc[8]; float bias = fb1[tid];
    #pragma unroll
    for (int bb=0;bb<8;bb++) acc[bb]=bias;
    for (int i=0;i<7;i++){ float wv = fw1m[i*128+tid];
      #pragma unroll
      for (int bb=0;bb<8;bb++) acc[bb] += wv*fs[bb][i]; }
    #pragma unroll
    for (int bb=0;bb<8;bb++) h1s[bb][tid]=fmaxf(acc[bb],0.f);
  }
  __syncthreads();
  {
    float acc[8]; float bias = fb2[tid];
    #pragma unroll
    for (int bb=0;bb<8;bb++) acc[bb]=bias;
    for (int i=0;i<128;i++){ float wv = fw2m[i*256+tid];
      #pragma unroll
      for (int bb=0;bb<8;bb++) acc[bb] += wv*h1s[bb][i]; }
    #pragma unroll
    for (int bb=0;bb<8;bb++) h2s[bb][tid]=fmaxf(acc[bb],0.f);
  }
  __syncthreads();
  #pragma unroll
  for (int oo=0;oo<2;oo++){
    int o = tid + oo*256;
    float acc[8]; float bias = fb3[o];
    #pragma unroll
    for (int bb=0;bb<8;bb++) acc[bb]=bias;
    for (int i=0;i<256;i++){ float wv = fw3m[i*512+o];
      #pragma unroll
      for (int bb=0;bb<8;bb++) acc[bb] += wv*h2s[bb][i]; }
    #pragma unroll
    for (int bb=0;bb<8;bb++){
      float v = fmaxf(acc[bb],0.f);
      fnnf[(size_t)(b0+bb)*CC + o] = v;
      fnnb[(size_t)(b0+bb)*CC + o] = f2bf(v);
    }
  }
}

// ---------------- generic 128x128 bf16 MFMA GEMM ----------------
enum { EP_RELU_BIAS=0, EP_RELU_BIAS_FATT=1, EP_LEAKY_BIAS=3, EP_BIAS_F32=4 };

template<int EP>
__global__ __launch_bounds__(256,3) void gemm_k(
    const ushort_t* __restrict__ A, const ushort_t* __restrict__ Bt,
    int K, int LoutA, int LinA, int CinA,
    const float* __restrict__ bias, const float* __restrict__ fatt,
    void* __restrict__ outp, int ldo)
{
  __shared__ __align__(16) ushort_t As[128*64];
  __shared__ __align__(16) ushort_t Bs[128*64];
  const int tid  = threadIdx.x;
  const int lane = tid & 63;
  const int w    = tid >> 6;
  int nx, my; swz_xy(nx, my);
  const int m0 = my * 128;
  const int n0 = nx * 128;
  const int chunk = (lane & 7) ^ (lane >> 3);

  const ushort_t* pa[4];
  const ushort_t* pb[4];
  #pragma unroll
  for (int it=0; it<4; ++it){
    int row = it*32 + w*8 + (lane>>3);
    int r = m0 + row;
    int bb = r / LoutA;
    int ll = r - bb*LoutA;
    pa[it] = A  + ((size_t)(bb*LinA + ll) * (size_t)CinA + (size_t)chunk*8);
    pb[it] = Bt + ((size_t)(n0+row) * (size_t)K + (size_t)chunk*8);
  }

  floatx4 acc[4][4];
  #pragma unroll
  for (int i=0;i<4;i++)
    #pragma unroll
    for (int j=0;j<4;j++) acc[i][j] = (floatx4){0.f,0.f,0.f,0.f};

  const int mw = (w & 1) * 64;
  const int nw = (w >> 1) * 64;

  for (int k0=0; k0<K; k0+=64){
    #pragma unroll
    for (int it=0; it<4; ++it){
      gld_lds16(pa[it], &As[(it*32 + w*8)*64]);
      gld_lds16(pb[it], &Bs[(it*32 + w*8)*64]);
      pa[it] += 64; pb[it] += 64;
    }
    __syncthreads();
    #pragma unroll
    for (int ks=0; ks<2; ++ks){
      bf16x8 af[4], bfr[4];
      #pragma unroll
      for (int i=0;i<4;i++){
        int rowa = mw + i*16 + (lane & 15);
        int rowb = nw + i*16 + (lane & 15);
        int j = ks*4 + (lane >> 4);
        af[i]  = *(const bf16x8*)&As[rowa*64 + ((j ^ (rowa & 7)) << 3)];
        bfr[i] = *(const bf16x8*)&Bs[rowb*64 + ((j ^ (rowb & 7)) << 3)];
      }
      #pragma unroll
      for (int i=0;i<4;i++)
        #pragma unroll
        for (int j=0;j<4;j++)
          acc[i][j] = __builtin_amdgcn_mfma_f32_16x16x32_bf16(af[i], bfr[j], acc[i][j], 0, 0, 0);
    }
    __syncthreads();
  }

  float* outf = (float*)outp;
  ushort_t* outh = (ushort_t*)outp;
  #pragma unroll
  for (int i=0;i<4;i++){
    #pragma unroll
    for (int j=0;j<4;j++){
      #pragma unroll
      for (int r4=0;r4<4;r4++){
        int m = m0 + mw + i*16 + (lane>>4)*4 + r4;
        int n = n0 + nw + j*16 + (lane & 15);
        float v = acc[i][j][r4] + bias[n];
        if constexpr (EP == EP_RELU_BIAS)       v = fmaxf(v, 0.f);
        else if constexpr (EP == EP_RELU_BIAS_FATT){ v += fatt[(m / L3)*CC + n]; v = fmaxf(v, 0.f); }
        else if constexpr (EP == EP_LEAKY_BIAS) v = v > 0.f ? v : 0.01f*v;
        if constexpr (EP == EP_BIAS_F32) outf[(size_t)m*ldo + n] = v;
        else                             outh[(size_t)m*ldo + n] = f2bf(v);
      }
    }
  }
}

// ---------------- fused attention: s = relu(dc@Wda^T+bda+fatt); A = s@Watt^T+batt;
//                  pooling (col-sum of A per batch, col-max of dc*(0.5+sig(A))) ----------------
// Block: 64 rows x 512 cols. s lives only in LDS (256-col halves).
__global__ __launch_bounds__(256,2) void att_k(
    const ushort_t* __restrict__ dcp,   // (rows, 512)
    const ushort_t* __restrict__ bWda,  // (512,512) [n][k]
    const float* __restrict__ bda,
    const float* __restrict__ fatt,     // (batches,512), chunk-local
    const ushort_t* __restrict__ bWatt, // (512,512) [n][k]
    const float* __restrict__ batt,
    float* __restrict__ asum_g, float* __restrict__ tmax_g)  // (batches,512), chunk-local, pre-zeroed
{
  __shared__ __align__(16) ushort_t Sh[64*256];   // 32 KB: s half (swizzled 8-col chunks)
  __shared__ __align__(16) ushort_t Bs[128*64];   // 16 KB
  __shared__ __align__(16) ushort_t AsR[64*64];   // 8 KB: dc staging, reused as reduction arrays
  float* red_sum = (float*)AsR;                   // [2][512]
  int*   red_max = (int*)AsR + 1024;              // [2][512]

  const int tid  = threadIdx.x;
  const int lane = tid & 63;
  const int w    = tid >> 6;
  const int m0   = blockIdx.x * 64;
  const int mh   = (w & 1) * 32;                  // wave tile 32 x 64
  const int nh   = (w >> 1) * 64;
  const int chunkb = (lane & 7) ^ (lane >> 3);

  const ushort_t* paBase[2];
  #pragma unroll
  for (int it=0; it<2; ++it)
    paBase[it] = dcp + (size_t)(m0 + it*32 + w*8 + (lane>>3))*CC + (size_t)chunkb*8;

  floatx4 acc2[4][2][4];
  #pragma unroll
  for (int a=0;a<4;a++)
    #pragma unroll
    for (int i=0;i<2;i++)
      #pragma unroll
      for (int j=0;j<4;j++) acc2[a][i][j] = (floatx4){0.f,0.f,0.f,0.f};

  for (int h=0; h<2; ++h){
    // ---- phase 1: s cols [h*256, h*256+256) -> Sh ----
    #pragma unroll
    for (int nt=0; nt<2; ++nt){
      floatx4 acc[2][4];
      #pragma unroll
      for (int i=0;i<2;i++)
        #pragma unroll
        for (int j=0;j<4;j++) acc[i][j] = (floatx4){0.f,0.f,0.f,0.f};
      const ushort_t* pa[2] = { paBase[0], paBase[1] };
      const ushort_t* pb[4];
      #pragma unroll
      for (int it=0; it<4; ++it)
        pb[it] = bWda + (size_t)(h*256 + nt*128 + it*32 + w*8 + (lane>>3))*CC + (size_t)chunkb*8;

      for (int k0=0; k0<512; k0+=64){
        #pragma unroll
        for (int it=0; it<2; ++it){ gld_lds16(pa[it], &AsR[(it*32 + w*8)*64]); pa[it] += 64; }
        #pragma unroll
        for (int it=0; it<4; ++it){ gld_lds16(pb[it], &Bs[(it*32 + w*8)*64]);  pb[it] += 64; }
        __syncthreads();
        #pragma unroll
        for (int ks=0; ks<2; ++ks){
          bf16x8 af[2], bfr[4];
          int j = ks*4 + (lane >> 4);
          #pragma unroll
          for (int i=0;i<2;i++){
            int rowa = mh + i*16 + (lane & 15);
            af[i] = *(const bf16x8*)&AsR[rowa*64 + ((j ^ (rowa & 7)) << 3)];
          }
          #pragma unroll
          for (int j2=0;j2<4;j2++){
            int rowb = nh + j2*16 + (lane & 15);
            bfr[j2] = *(const bf16x8*)&Bs[rowb*64 + ((j ^ (rowb & 7)) << 3)];
          }
          #pragma unroll
          for (int i=0;i<2;i++)
            #pragma unroll
            for (int j2=0;j2<4;j2++)
              acc[i][j2] = __builtin_amdgcn_mfma_f32_16x16x32_bf16(af[i], bfr[j2], acc[i][j2], 0, 0, 0);
        }
        __syncthreads();
      }
      // epilogue: relu(acc + bda + fatt) -> Sh (swizzled)
      #pragma unroll
      for (int i=0;i<2;i++){
        #pragma unroll
        for (int j2=0;j2<4;j2++){
          #pragma unroll
          for (int r4=0;r4<4;r4++){
            int row = mh + i*16 + (lane>>4)*4 + r4;
            int cl  = nt*128 + nh + j2*16 + (lane & 15);
            int gn  = h*256 + cl;
            float v = acc[i][j2][r4] + bda[gn] + fatt[(size_t)((m0+row)/L3)*CC + gn];
            v = fmaxf(v, 0.f);
            Sh[row*256 + ((((cl>>3) ^ (row & 7)) << 3) | (cl & 7))] = f2bf(v);
          }
        }
      }
    }
    __syncthreads();   // Sh complete for this half

    // ---- phase 2: acc2 += s_half @ Watt^T(:, half) ----
    #pragma unroll
    for (int nt2=0; nt2<4; ++nt2){
      const ushort_t* pb[4];
      #pragma unroll
      for (int it=0; it<4; ++it)
        pb[it] = bWatt + (size_t)(nt2*128 + it*32 + w*8 + (lane>>3))*CC + h*256 + (size_t)chunkb*8;
      for (int k0=0; k0<256; k0+=64){
        #pragma unroll
        for (int it=0; it<4; ++it){ gld_lds16(pb[it], &Bs[(it*32 + w*8)*64]); pb[it] += 64; }
        __syncthreads();
        #pragma unroll
        for (int ks=0; ks<2; ++ks){
          bf16x8 af[2], bfr[4];
          int j = ks*4 + (lane >> 4);
          int cj = (k0 >> 3) + j;
          #pragma unroll
          for (int i=0;i<2;i++){
            int row = mh + i*16 + (lane & 15);
            af[i] = *(const bf16x8*)&Sh[row*256 + ((cj ^ (row & 7)) << 3)];
          }
          #pragma unroll
          for (int j2=0;j2<4;j2++){
            int rowb = nh + j2*16 + (lane & 15);
            bfr[j2] = *(const bf16x8*)&Bs[rowb*64 + ((j ^ (rowb & 7)) << 3)];
          }
          #pragma unroll
          for (int i=0;i<2;i++)
            #pragma unroll
            for (int j2=0;j2<4;j2++)
              acc2[nt2][i][j2] = __builtin_amdgcn_mfma_f32_16x16x32_bf16(af[i], bfr[j2], acc2[nt2][i][j2], 0, 0, 0);
        }
        __syncthreads();
      }
    }
  }

  // ---- pooling epilogue (AsR now dead -> reduction arrays) ----
  for (int t2 = tid; t2 < 1024; t2 += 256){ red_sum[t2] = 0.f; red_max[t2] = 0; }
  __syncthreads();
  const int bfirst = m0 / L3;
  const int segW = (m0 + mh) / L3 - bfirst;           // 0 or 1; wave rows cross <=1 boundary
  #pragma unroll
  for (int nt2=0; nt2<4; ++nt2){
    #pragma unroll
    for (int j2=0;j2<4;j2++){
      int n = nt2*128 + nh + j2*16 + (lane & 15);
      float s0=0.f, s1=0.f, x0=0.f, x1=0.f;
      float bi = batt[n];
      #pragma unroll
      for (int i=0;i<2;i++){
        #pragma unroll
        for (int r4=0;r4<4;r4++){
          int m = m0 + mh + i*16 + (lane>>4)*4 + r4;
          float Av = acc2[nt2][i][j2][r4] + bi;
          float dcv = bf2f(dcp[(size_t)m*CC + n]);
          float tv = dcv * (0.5f + sigmoidf_(Av));
          if (m / L3 - bfirst == segW){ s0 += Av; x0 = fmaxf(x0, tv); }
          else                        { s1 += Av; x1 = fmaxf(x1, tv); }
        }
      }
      atomicAdd(&red_sum[segW*512 + n], s0);
      atomicMax(&red_max[segW*512 + n], __float_as_int(x0));
      if (segW == 0){
        atomicAdd(&red_sum[512 + n], s1);
        atomicMax(&red_max[512 + n], __float_as_int(x1));
      }
    }
  }
  __syncthreads();
  for (int t2 = tid; t2 < 1024; t2 += 256){
    int seg = t2 >> 9, col = t2 & 511;
    int b = bfirst + seg;
    if (b*L3 < m0 + 64 && b*L3 + L3 > m0){
      atomicAdd(asum_g + (size_t)b*CC + col, red_sum[t2]);
      atomicMax((int*)tmax_g + (size_t)b*CC + col, red_max[t2]);
    }
  }
}

// ---------------- finish pooling ----------------
__global__ void reduce2_k(const float* __restrict__ asum, const float* __restrict__ tmax,
                          const float* __restrict__ fnnf, ushort_t* __restrict__ pair)
{
  int g = blockIdx.x * blockDim.x + threadIdx.x;
  if (g >= BN * CC) return;
  int b = g >> 9, c = g & 511;
  pair[(size_t)b*1024 + c] = f2bf(tmax[g]);
  float fv = fnnf[g] * (0.5f + sigmoidf_(asum[g] * (1.f/(float)L3)));
  pair[(size_t)b*1024 + 512 + c] = f2bf(fv);
}

// ---------------- final dot ----------------
__global__ void final_k(const ushort_t* __restrict__ h3, const float* __restrict__ Wo,
                        const float* __restrict__ bo, float* __restrict__ out)
{
  int b = blockIdx.x*4 + (threadIdx.x >> 6);
  int lane = threadIdx.x & 63;
  float acc = 0.f;
  for (int i=lane; i<512; i+=64) acc += bf2f(h3[(size_t)b*512 + i]) * Wo[i];
  #pragma unroll
  for (int off=32; off; off>>=1) acc += __shfl_down(acc, off);
  if (lane == 0) out[b] = acc + bo[0];
}

// ---------------- host ----------------
extern "C" void kernel_launch(void* const* d_in, const int* in_sizes, int n_in,
                              void* d_out, int out_size, void* d_ws, size_t ws_size,
                              hipStream_t stream)
{
  (void)in_sizes; (void)n_in; (void)out_size;
  const int*   drug    = (const int*)  d_in[0];
  const float* feature = (const float*)d_in[1];
  const float* emb     = (const float*)d_in[2];
  const float* dw1 = (const float*)d_in[3];  const float* db1 = (const float*)d_in[4];
  const float* dw2 = (const float*)d_in[5];  const float* db2 = (const float*)d_in[6];
  const float* dw3 = (const float*)d_in[7];  const float* db3 = (const float*)d_in[8];
  const float* fw1 = (const float*)d_in[9];  const float* fb1 = (const float*)d_in[10];
  const float* fw2 = (const float*)d_in[11]; const float* fb2 = (const float*)d_in[12];
  const float* fw3 = (const float*)d_in[13]; const float* fb3 = (const float*)d_in[14];
  const float* Wda = (const float*)d_in[15]; const float* bda = (const float*)d_in[16];
  const float* Wfa = (const float*)d_in[17]; const float* bfa = (const float*)d_in[18];
  const float* Watt= (const float*)d_in[19]; const float* batt= (const float*)d_in[20];
  const float* W1  = (const float*)d_in[21]; const float* b1  = (const float*)d_in[22];
  const float* W2  = (const float*)d_in[23]; const float* b2  = (const float*)d_in[24];
  const float* W3  = (const float*)d_in[25]; const float* b3  = (const float*)d_in[26];
  const float* Wo  = (const float*)d_in[27]; const float* bo  = (const float*)d_in[28];
  float* out = (float*)d_out;

  size_t off = 0; char* base = (char*)d_ws;
  auto alloc = [&](size_t bytes)->char*{
    off = (off + 255) & ~(size_t)255; char* p = base + off; off += bytes; return p;
  };
  ushort_t* bt1  = (ushort_t*)alloc(128*512*2);
  ushort_t* bt2  = (ushort_t*)alloc(256*768*2);
  ushort_t* bt3  = (ushort_t*)alloc((size_t)512*2048*2);
  ushort_t* bWda = (ushort_t*)alloc(262144*2);
  ushort_t* bWfa = (ushort_t*)alloc(262144*2);
  ushort_t* bWatt= (ushort_t*)alloc(262144*2);
  ushort_t* bW1  = (ushort_t*)alloc((size_t)1048576*2);
  ushort_t* bW2  = (ushort_t*)alloc((size_t)1048576*2);
  ushort_t* bW3  = (ushort_t*)alloc((size_t)524288*2);
  float* fw1m = (float*)alloc(7*128*4);
  float* fw2m = (float*)alloc(128*256*4);
  float* fw3m = (float*)alloc(256*512*4);
  float* fnnf = (float*)alloc((size_t)BN*CC*4);
  ushort_t* fnnb = (ushort_t*)alloc((size_t)BN*CC*2);
  float* fattf = (float*)alloc((size_t)BN*CC*4);
  float* asum_g = (float*)alloc((size_t)BN*CC*4);
  float* tmax_g = (float*)alloc((size_t)BN*CC*4);
  ushort_t* pairb = (ushort_t*)alloc((size_t)BN*1024*2);
  ushort_t* m1b = (ushort_t*)alloc((size_t)BN*1024*2);
  ushort_t* m2b = (ushort_t*)alloc((size_t)BN*1024*2);
  ushort_t* m3b = (ushort_t*)alloc((size_t)BN*512*2);

  // per-batch bytes: xemb 25600 + h1 24832 + h2 47104 = 97536 (slabP), dc 87040
  const size_t PER_SLABP = 97536, PER_DC = 87040, PER_CHUNK = PER_SLABP + PER_DC;
  size_t avail = (ws_size > off + 4096) ? (ws_size - off - 4096) : 0;
  int CH = (int)(avail / PER_CHUNK);
  if (CH > BN) CH = BN;
  CH = (CH / 128) * 128;
  if (CH < 128) CH = 128;
  char* chunkbase = alloc((size_t)CH*PER_CHUNK);
  ushort_t* xembC = (ushort_t*)chunkbase;
  ushort_t* h1C   = (ushort_t*)(chunkbase + (size_t)CH*25600);
  ushort_t* h2C   = (ushort_t*)(chunkbase + (size_t)CH*(25600+24832));
  ushort_t* dcC   = (ushort_t*)(chunkbase + (size_t)CH*PER_SLABP);

  PrepArgs pa;
  pa.dw1=dw1; pa.dw2=dw2; pa.dw3=dw3; pa.Wda=Wda; pa.Wfa=Wfa; pa.Watt=Watt;
  pa.W1=W1; pa.W2=W2; pa.W3=W3; pa.fw1=fw1; pa.fw2=fw2; pa.fw3=fw3;
  pa.bt1=bt1; pa.bt2=bt2; pa.bt3=bt3; pa.bWda=bWda; pa.bWfa=bWfa; pa.bWatt=bWatt;
  pa.bW1=bW1; pa.bW2=bW2; pa.bW3=bW3; pa.fw1m=fw1m; pa.fw2m=fw2m; pa.fw3m=fw3m;

  hipMemsetAsync(asum_g, 0, (size_t)BN*CC*4, stream);
  hipMemsetAsync(tmax_g, 0, (size_t)BN*CC*4, stream);
  prep_k<<<dim3(64,12), 256, 0, stream>>>(pa);
  featnn_k<<<BN/8, 256, 0, stream>>>(feature, fw1m, fb1, fw2m, fb2, fw3m, fb3, fnnf, fnnb);
  gemm_k<EP_BIAS_F32><<<dim3(4,16), 256, 0, stream>>>(fnnb, bWfa, 512, 1,1,512, bfa, nullptr, fattf, 512);

  for (int b0c = 0; b0c < BN; b0c += CH){
    const int c = (BN - b0c < CH) ? (BN - b0c) : CH;
    const int t = c / 128;                           // 128-batch groups
    gather_k<<<(c*LD*(DIM/8) + 255)/256, 256, 0, stream>>>(drug + (size_t)b0c*LD, emb, xembC, c*LD*(DIM/8));
    gemm_k<EP_RELU_BIAS><<<dim3(1, t*L1), 256, 0, stream>>>(xembC, bt1, 512,  L1, LD, DIM, db1, nullptr, h1C, 128);
    gemm_k<EP_RELU_BIAS><<<dim3(2, t*L2), 256, 0, stream>>>(h1C,  bt2, 768,  L2, L1, 128, db2, nullptr, h2C, 256);
    gemm_k<EP_RELU_BIAS><<<dim3(4, t*L3), 256, 0, stream>>>(h2C,  bt3, 2048, L3, L2, 256, db3, nullptr, dcC,  512);
    att_k<<<dim3(t*170), 256, 0, stream>>>(dcC, bWda, bda, fattf + (size_t)b0c*CC, bWatt, batt,
                                           asum_g + (size_t)b0c*CC, tmax_g + (size_t)b0c*CC);
  }

  reduce2_k<<<(BN*CC + 255)/256, 256, 0, stream>>>(asum_g, tmax_g, fnnf, pairb);

  gemm_k<EP_LEAKY_BIAS><<<dim3(8,16), 256, 0, stream>>>(pairb, bW1, 1024, 1,1,1024, b1, nullptr, m1b, 1024);
  gemm_k<EP_LEAKY_BIAS><<<dim3(8,16), 256, 0, stream>>>(m1b,  bW2, 1024, 1,1,1024, b2, nullptr, m2b, 1024);
  gemm_k<EP_LEAKY_BIAS><<<dim3(4,16), 256, 0, stream>>>(m2b,  bW3, 1024, 1,1,1024, b3, nullptr, m3b, 512);
  final_k<<<BN/4, 256, 0, stream>>>(m3b, Wo, bo, out);
}

// Round 6
// 1071.020 us; speedup vs baseline: 1.5001x; 1.5001x over previous
//
#include <hip/hip_runtime.h>
#include <cstdint>
#include <cstddef>

typedef unsigned short ushort_t;
typedef __bf16 bf16x8 __attribute__((ext_vector_type(8)));
typedef float floatx4 __attribute__((ext_vector_type(4)));

#define DEV static __device__ __forceinline__

DEV ushort_t f2bf(float f){
  union { float f; uint32_t u; } v; v.f = f;
  uint32_t u = v.u;
  return (ushort_t)((u + 0x7fffu + ((u >> 16) & 1u)) >> 16);
}
DEV float bf2f(ushort_t h){
  union { uint32_t u; float f; } v; v.u = ((uint32_t)h) << 16; return v.f;
}
DEV float sigmoidf_(float x){ return 1.f / (1.f + __expf(-x)); }

#define AS1 __attribute__((address_space(1)))
#define AS3 __attribute__((address_space(3)))
DEV void gld_lds16(const void* g, void* l){
  __builtin_amdgcn_global_load_lds((const AS1 void*)g, (AS3 void*)l, 16, 0, 0);
}

// XCD-locality swizzle: all x-tiles (n) of one y-tile (m) land on the same XCD.
DEV void swz_xy(int& nx, int& my){
  int gx = gridDim.x, gy = gridDim.y;
  int lin = blockIdx.x + gx * blockIdx.y;
  int full = gy & ~7;
  int region = full * gx;
  if (lin < region){ int q = lin >> 3; nx = q % gx; my = (q / gx) * 8 + (lin & 7); }
  else { int r = lin - region; nx = r % gx; my = full + r / gx; }
}

// ---------------- problem constants ----------------
#define BN 2048
#define LD 100
#define DIM 128
#define L1 97   // after k=4
#define L2 92   // after k=6
#define L3 85   // after k=8
#define CC 512  // C = CONV*4

// ---------------- prep: weight transforms + casts ----------------
struct PrepArgs {
  const float *dw1,*dw2,*dw3,*Wda,*Wfa,*Watt,*W1,*W2,*W3,*fw1,*fw2,*fw3;
  ushort_t *bt1,*bt2,*bt3,*bWda,*bWfa,*bWatt,*bW1,*bW2,*bW3;
  float *fw1m,*fw2m,*fw3m;
};

__global__ void prep_k(PrepArgs a){
  int t0 = blockIdx.x * blockDim.x + threadIdx.x;
  int stride = gridDim.x * blockDim.x;
  switch (blockIdx.y){
  case 0:
    for (int i=t0;i<128*512;i+=stride){ int o=i>>9, rem=i&511, kk=rem>>7, c=rem&127;
      a.bt1[i]=f2bf(a.dw1[o*512 + c*4 + kk]); } break;
  case 1:
    for (int i=t0;i<256*768;i+=stride){ int o=i/768, rem=i-o*768, kk=rem>>7, c=rem&127;
      a.bt2[i]=f2bf(a.dw2[o*768 + c*6 + kk]); } break;
  case 2:
    for (int i=t0;i<512*2048;i+=stride){ int o=i>>11, rem=i&2047, kk=rem>>8, c=rem&255;
      a.bt3[i]=f2bf(a.dw3[o*2048 + c*8 + kk]); } break;
  case 3: for (int i=t0;i<262144;i+=stride) a.bWda[i]=f2bf(a.Wda[i]); break;
  case 4: for (int i=t0;i<262144;i+=stride) a.bWfa[i]=f2bf(a.Wfa[i]); break;
  case 5: for (int i=t0;i<262144;i+=stride) a.bWatt[i]=f2bf(a.Watt[i]); break;
  case 6: for (int i=t0;i<1048576;i+=stride) a.bW1[i]=f2bf(a.W1[i]); break;
  case 7: for (int i=t0;i<1048576;i+=stride) a.bW2[i]=f2bf(a.W2[i]); break;
  case 8: for (int i=t0;i<524288;i+=stride) a.bW3[i]=f2bf(a.W3[i]); break;
  case 9:  for (int i=t0;i<7*128;i+=stride){ int ii=i>>7, o=i&127; a.fw1m[i]=a.fw1[o*21 + ii*3 + 1]; } break;
  case 10: for (int i=t0;i<128*256;i+=stride){ int ii=i>>8, o=i&255; a.fw2m[i]=a.fw2[o*384 + ii*3 + 1]; } break;
  case 11: for (int i=t0;i<256*512;i+=stride){ int ii=i>>9, o=i&511; a.fw3m[i]=a.fw3[o*768 + ii*3 + 1]; } break;
  }
}

// ---------------- feature NN ----------------
__global__ void featnn_k(const float* __restrict__ feature,
                         const float* __restrict__ fw1m, const float* __restrict__ fb1,
                         const float* __restrict__ fw2m, const float* __restrict__ fb2,
                         const float* __restrict__ fw3m, const float* __restrict__ fb3,
                         float* __restrict__ fnnf, ushort_t* __restrict__ fnnb)
{
  __shared__ float fs[8][7];
  __shared__ float h1s[8][128];
  __shared__ float h2s[8][256];
  int b0 = blockIdx.x * 8;
  int tid = threadIdx.x;
  if (tid < 56){ int bb = tid/7, i = tid - bb*7; fs[bb][i] = feature[(b0+bb)*7 + i]; }
  __syncthreads();
  if (tid < 128){
    float acc[8]; float bias = fb1[tid];
    #pragma unroll
    for (int bb=0;bb<8;bb++) acc[bb]=bias;
    for (int i=0;i<7;i++){ float wv = fw1m[i*128+tid];
      #pragma unroll
      for (int bb=0;bb<8;bb++) acc[bb] += wv*fs[bb][i]; }
    #pragma unroll
    for (int bb=0;bb<8;bb++) h1s[bb][tid]=fmaxf(acc[bb],0.f);
  }
  __syncthreads();
  {
    float acc[8]; float bias = fb2[tid];
    #pragma unroll
    for (int bb=0;bb<8;bb++) acc[bb]=bias;
    for (int i=0;i<128;i++){ float wv = fw2m[i*256+tid];
      #pragma unroll
      for (int bb=0;bb<8;bb++) acc[bb] += wv*h1s[bb][i]; }
    #pragma unroll
    for (int bb=0;bb<8;bb++) h2s[bb][tid]=fmaxf(acc[bb],0.f);
  }
  __syncthreads();
  #pragma unroll
  for (int oo=0;oo<2;oo++){
    int o = tid + oo*256;
    float acc[8]; float bias = fb3[o];
    #pragma unroll
    for (int bb=0;bb<8;bb++) acc[bb]=bias;
    for (int i=0;i<256;i++){ float wv = fw3m[i*512+o];
      #pragma unroll
      for (int bb=0;bb<8;bb++) acc[bb] += wv*h2s[bb][i]; }
    #pragma unroll
    for (int bb=0;bb<8;bb++){
      float v = fmaxf(acc[bb],0.f);
      fnnf[(size_t)(b0+bb)*CC + o] = v;
      fnnb[(size_t)(b0+bb)*CC + o] = f2bf(v);
    }
  }
}

// ---------------- conv1 with embedding table resident in LDS ----------------
// A-fragment = emb[drug[b, l+kk]][c0..c0+7] read straight from LDS (no xemb).
// Emb rows padded to 136 elems: 272 B stride => 16B-aligned b128 reads, random
// tokens spread over 8 bank offsets (~2-way, free per m136).
__global__ __launch_bounds__(256,3) void conv1_k(
    const int* __restrict__ drug,      // chunk-local (batches,100)
    const float* __restrict__ emb,     // (65,128) fp32
    const ushort_t* __restrict__ bt1,  // (128, 512) [o][kk*128+c]
    const float* __restrict__ db1,
    ushort_t* __restrict__ h1)         // (batches*97, 128)
{
  __shared__ __align__(16) ushort_t Bs[128*64];
  __shared__ __align__(16) ushort_t Emb[65*136];
  __shared__ uint8_t Tok[128*4];
  const int tid  = threadIdx.x;
  const int lane = tid & 63;
  const int w    = tid >> 6;
  const int m0   = blockIdx.x * 128;

  for (int idx = tid; idx < 65*128; idx += 256){
    int t2 = idx >> 7, c = idx & 127;
    Emb[t2*136 + c] = f2bf(emb[idx]);
  }
  for (int idx = tid; idx < 128*4; idx += 256){
    int row = idx >> 2, kk = idx & 3;
    int r = m0 + row;
    int b = r / L1, l = r - b*L1;
    Tok[idx] = (uint8_t)drug[b*LD + l + kk];   // l+kk <= 96+3 < 100
  }

  const int chunk = (lane & 7) ^ (lane >> 3);
  const ushort_t* pb[4];
  #pragma unroll
  for (int it=0; it<4; ++it)
    pb[it] = bt1 + (size_t)(it*32 + w*8 + (lane>>3))*512 + (size_t)chunk*8;

  floatx4 acc[4][4];
  #pragma unroll
  for (int i=0;i<4;i++)
    #pragma unroll
    for (int j=0;j<4;j++) acc[i][j] = (floatx4){0.f,0.f,0.f,0.f};

  const int mw = (w & 1) * 64;
  const int nw = (w >> 1) * 64;

  for (int k0=0; k0<512; k0+=64){
    #pragma unroll
    for (int it=0; it<4; ++it){ gld_lds16(pb[it], &Bs[(it*32 + w*8)*64]); pb[it] += 64; }
    __syncthreads();                       // also covers Emb/Tok on first iter
    #pragma unroll
    for (int ks=0; ks<2; ++ks){
      int j  = ks*4 + (lane >> 4);
      int kg = k0 + j*8;
      int kk = kg >> 7, c0 = kg & 127;
      bf16x8 af[4], bfr[4];
      #pragma unroll
      for (int i=0;i<4;i++){
        int rowa = mw + i*16 + (lane & 15);
        int tok = Tok[rowa*4 + kk];
        af[i] = *(const bf16x8*)&Emb[tok*136 + c0];
      }
      #pragma unroll
      for (int j2=0;j2<4;j2++){
        int rowb = nw + j2*16 + (lane & 15);
        bfr[j2] = *(const bf16x8*)&Bs[rowb*64 + ((j ^ (rowb & 7)) << 3)];
      }
      #pragma unroll
      for (int i=0;i<4;i++)
        #pragma unroll
        for (int j2=0;j2<4;j2++)
          acc[i][j2] = __builtin_amdgcn_mfma_f32_16x16x32_bf16(af[i], bfr[j2], acc[i][j2], 0, 0, 0);
    }
    __syncthreads();
  }

  #pragma unroll
  for (int i=0;i<4;i++){
    #pragma unroll
    for (int j2=0;j2<4;j2++){
      #pragma unroll
      for (int r4=0;r4<4;r4++){
        int r = m0 + mw + i*16 + (lane>>4)*4 + r4;
        int n = nw + j2*16 + (lane & 15);
        float v = fmaxf(acc[i][j2][r4] + db1[n], 0.f);
        h1[(size_t)r*128 + n] = f2bf(v);
      }
    }
  }
}

// ---------------- generic 128x128 bf16 MFMA GEMM ----------------
enum { EP_RELU_BIAS=0, EP_RELU_BIAS_FATT=1, EP_ATT=2, EP_LEAKY_BIAS=3, EP_BIAS_F32=4 };

template<int EP>
__global__ __launch_bounds__(256,3) void gemm_k(
    const ushort_t* __restrict__ A, const ushort_t* __restrict__ Bt,
    int K, int LoutA, int LinA, int CinA,
    const float* __restrict__ bias, const float* __restrict__ fatt,
    void* __restrict__ outp, int ldo,
    const ushort_t* __restrict__ dcp, float* __restrict__ asum_g, float* __restrict__ tmax_g)
{
  __shared__ __align__(16) ushort_t As[128*64];
  __shared__ __align__(16) ushort_t Bs[128*64];
  const int tid  = threadIdx.x;
  const int lane = tid & 63;
  const int w    = tid >> 6;
  int nx, my; swz_xy(nx, my);
  const int m0 = my * 128;
  const int n0 = nx * 128;
  const int chunk = (lane & 7) ^ (lane >> 3);

  const ushort_t* pa[4];
  const ushort_t* pb[4];
  #pragma unroll
  for (int it=0; it<4; ++it){
    int row = it*32 + w*8 + (lane>>3);
    int r = m0 + row;
    int bb = r / LoutA;
    int ll = r - bb*LoutA;
    pa[it] = A  + ((size_t)(bb*LinA + ll) * (size_t)CinA + (size_t)chunk*8);
    pb[it] = Bt + ((size_t)(n0+row) * (size_t)K + (size_t)chunk*8);
  }

  floatx4 acc[4][4];
  #pragma unroll
  for (int i=0;i<4;i++)
    #pragma unroll
    for (int j=0;j<4;j++) acc[i][j] = (floatx4){0.f,0.f,0.f,0.f};

  const int mw = (w & 1) * 64;
  const int nw = (w >> 1) * 64;

  for (int k0=0; k0<K; k0+=64){
    #pragma unroll
    for (int it=0; it<4; ++it){
      gld_lds16(pa[it], &As[(it*32 + w*8)*64]);
      gld_lds16(pb[it], &Bs[(it*32 + w*8)*64]);
      pa[it] += 64; pb[it] += 64;
    }
    __syncthreads();
    #pragma unroll
    for (int ks=0; ks<2; ++ks){
      bf16x8 af[4], bfr[4];
      #pragma unroll
      for (int i=0;i<4;i++){
        int rowa = mw + i*16 + (lane & 15);
        int rowb = nw + i*16 + (lane & 15);
        int j = ks*4 + (lane >> 4);
        af[i]  = *(const bf16x8*)&As[rowa*64 + ((j ^ (rowa & 7)) << 3)];
        bfr[i] = *(const bf16x8*)&Bs[rowb*64 + ((j ^ (rowb & 7)) << 3)];
      }
      #pragma unroll
      for (int i=0;i<4;i++)
        #pragma unroll
        for (int j=0;j<4;j++)
          acc[i][j] = __builtin_amdgcn_mfma_f32_16x16x32_bf16(af[i], bfr[j], acc[i][j], 0, 0, 0);
    }
    __syncthreads();
  }

  if constexpr (EP == EP_ATT){
    __shared__ float red_sum[3*128];
    __shared__ int   red_max[3*128];
    const int bfirst = m0 / L3;
    for (int t2 = tid; t2 < 3*128; t2 += 256){ red_sum[t2] = 0.f; red_max[t2] = 0; }
    __syncthreads();
    const int segA = (m0 + mw) / L3 - bfirst;
    #pragma unroll
    for (int j=0;j<4;j++){
      int col = nw + j*16 + (lane & 15);
      int n = n0 + col;
      float bi = bias[n];
      float s0 = 0.f, s1 = 0.f, x0 = 0.f, x1 = 0.f;
      #pragma unroll
      for (int i=0;i<4;i++){
        #pragma unroll
        for (int r4=0;r4<4;r4++){
          int m = m0 + mw + i*16 + (lane>>4)*4 + r4;
          float Av = acc[i][j][r4] + bi;
          float dcv = bf2f(dcp[(size_t)m*CC + n]);
          float tv = dcv * (0.5f + sigmoidf_(Av));
          if ((m / L3 - bfirst) == segA){ s0 += Av; x0 = fmaxf(x0, tv); }
          else                          { s1 += Av; x1 = fmaxf(x1, tv); }
        }
      }
      atomicAdd(&red_sum[segA*128 + col], s0);
      atomicMax(&red_max[segA*128 + col], __float_as_int(x0));
      if (segA + 1 < 3){
        atomicAdd(&red_sum[(segA+1)*128 + col], s1);
        atomicMax(&red_max[(segA+1)*128 + col], __float_as_int(x1));
      }
    }
    __syncthreads();
    for (int t2 = tid; t2 < 3*128; t2 += 256){
      int seg = t2 >> 7, col = t2 & 127;
      int b = bfirst + seg;
      if (b * L3 < m0 + 128){
        atomicAdd(asum_g + (size_t)b*CC + n0 + col, red_sum[t2]);
        atomicMax((int*)tmax_g + (size_t)b*CC + n0 + col, red_max[t2]);
      }
    }
    return;
  }

  float* outf = (float*)outp;
  ushort_t* outh = (ushort_t*)outp;
  #pragma unroll
  for (int i=0;i<4;i++){
    #pragma unroll
    for (int j=0;j<4;j++){
      #pragma unroll
      for (int r4=0;r4<4;r4++){
        int m = m0 + mw + i*16 + (lane>>4)*4 + r4;
        int n = n0 + nw + j*16 + (lane & 15);
        float v = acc[i][j][r4] + bias[n];
        if constexpr (EP == EP_RELU_BIAS)       v = fmaxf(v, 0.f);
        else if constexpr (EP == EP_RELU_BIAS_FATT){ v += fatt[(m / L3)*CC + n]; v = fmaxf(v, 0.f); }
        else if constexpr (EP == EP_LEAKY_BIAS) v = v > 0.f ? v : 0.01f*v;
        if constexpr (EP == EP_BIAS_F32) outf[(size_t)m*ldo + n] = v;
        else                             outh[(size_t)m*ldo + n] = f2bf(v);
      }
    }
  }
}

// ---------------- finish pooling ----------------
__global__ void reduce2_k(const float* __restrict__ asum, const float* __restrict__ tmax,
                          const float* __restrict__ fnnf, ushort_t* __restrict__ pair)
{
  int g = blockIdx.x * blockDim.x + threadIdx.x;
  if (g >= BN * CC) return;
  int b = g >> 9, c = g & 511;
  pair[(size_t)b*1024 + c] = f2bf(tmax[g]);
  float fv = fnnf[g] * (0.5f + sigmoidf_(asum[g] * (1.f/(float)L3)));
  pair[(size_t)b*1024 + 512 + c] = f2bf(fv);
}

// ---------------- final dot ----------------
__global__ void final_k(const ushort_t* __restrict__ h3, const float* __restrict__ Wo,
                        const float* __restrict__ bo, float* __restrict__ out)
{
  int b = blockIdx.x*4 + (threadIdx.x >> 6);
  int lane = threadIdx.x & 63;
  float acc = 0.f;
  for (int i=lane; i<512; i+=64) acc += bf2f(h3[(size_t)b*512 + i]) * Wo[i];
  #pragma unroll
  for (int off=32; off; off>>=1) acc += __shfl_down(acc, off);
  if (lane == 0) out[b] = acc + bo[0];
}

// ---------------- host ----------------
extern "C" void kernel_launch(void* const* d_in, const int* in_sizes, int n_in,
                              void* d_out, int out_size, void* d_ws, size_t ws_size,
                              hipStream_t stream)
{
  (void)in_sizes; (void)n_in; (void)out_size;
  const int*   drug    = (const int*)  d_in[0];
  const float* feature = (const float*)d_in[1];
  const float* emb     = (const float*)d_in[2];
  const float* dw1 = (const float*)d_in[3];  const float* db1 = (const float*)d_in[4];
  const float* dw2 = (const float*)d_in[5];  const float* db2 = (const float*)d_in[6];
  const float* dw3 = (const float*)d_in[7];  const float* db3 = (const float*)d_in[8];
  const float* fw1 = (const float*)d_in[9];  const float* fb1 = (const float*)d_in[10];
  const float* fw2 = (const float*)d_in[11]; const float* fb2 = (const float*)d_in[12];
  const float* fw3 = (const float*)d_in[13]; const float* fb3 = (const float*)d_in[14];
  const float* Wda = (const float*)d_in[15]; const float* bda = (const float*)d_in[16];
  const float* Wfa = (const float*)d_in[17]; const float* bfa = (const float*)d_in[18];
  const float* Watt= (const float*)d_in[19]; const float* batt= (const float*)d_in[20];
  const float* W1  = (const float*)d_in[21]; const float* b1  = (const float*)d_in[22];
  const float* W2  = (const float*)d_in[23]; const float* b2  = (const float*)d_in[24];
  const float* W3  = (const float*)d_in[25]; const float* b3  = (const float*)d_in[26];
  const float* Wo  = (const float*)d_in[27]; const float* bo  = (const float*)d_in[28];
  float* out = (float*)d_out;

  size_t off = 0; char* base = (char*)d_ws;
  auto alloc = [&](size_t bytes)->char*{
    off = (off + 255) & ~(size_t)255; char* p = base + off; off += bytes; return p;
  };
  ushort_t* bt1  = (ushort_t*)alloc(128*512*2);
  ushort_t* bt2  = (ushort_t*)alloc(256*768*2);
  ushort_t* bt3  = (ushort_t*)alloc((size_t)512*2048*2);
  ushort_t* bWda = (ushort_t*)alloc(262144*2);
  ushort_t* bWfa = (ushort_t*)alloc(262144*2);
  ushort_t* bWatt= (ushort_t*)alloc(262144*2);
  ushort_t* bW1  = (ushort_t*)alloc((size_t)1048576*2);
  ushort_t* bW2  = (ushort_t*)alloc((size_t)1048576*2);
  ushort_t* bW3  = (ushort_t*)alloc((size_t)524288*2);
  float* fw1m = (float*)alloc(7*128*4);
  float* fw2m = (float*)alloc(128*256*4);
  float* fw3m = (float*)alloc(256*512*4);
  float* fnnf = (float*)alloc((size_t)BN*CC*4);
  ushort_t* fnnb = (ushort_t*)alloc((size_t)BN*CC*2);
  float* fattf = (float*)alloc((size_t)BN*CC*4);
  float* asum_g = (float*)alloc((size_t)BN*CC*4);
  float* tmax_g = (float*)alloc((size_t)BN*CC*4);
  ushort_t* pairb = (ushort_t*)alloc((size_t)BN*1024*2);
  ushort_t* m1b = (ushort_t*)alloc((size_t)BN*1024*2);
  ushort_t* m2b = (ushort_t*)alloc((size_t)BN*1024*2);
  ushort_t* m3b = (ushort_t*)alloc((size_t)BN*512*2);

  // Ping-pong chunk buffers: bufB holds h1 then dc; bufA holds h2 then s.
  // Liveness: conv1->B, conv2 B->A, conv3 A->B (h1 dead), Wda B->A (h2 dead),
  // Watt reads A(s)+B(dc). Per-batch per buffer = dc/s size = 85*512*2 = 87040.
  const size_t PER_BUF = 87040, PER_CHUNK = 2*PER_BUF;
  size_t avail = (ws_size > off + 4096) ? (ws_size - off - 4096) : 0;
  int CH = (int)(avail / PER_CHUNK);
  if (CH > BN) CH = BN;
  CH = (CH / 128) * 128;
  if (CH < 128) CH = 128;
  char* chunkbase = alloc((size_t)CH*PER_CHUNK);
  ushort_t* bufA = (ushort_t*)chunkbase;
  ushort_t* bufB = (ushort_t*)(chunkbase + (size_t)CH*PER_BUF);

  PrepArgs pa;
  pa.dw1=dw1; pa.dw2=dw2; pa.dw3=dw3; pa.Wda=Wda; pa.Wfa=Wfa; pa.Watt=Watt;
  pa.W1=W1; pa.W2=W2; pa.W3=W3; pa.fw1=fw1; pa.fw2=fw2; pa.fw3=fw3;
  pa.bt1=bt1; pa.bt2=bt2; pa.bt3=bt3; pa.bWda=bWda; pa.bWfa=bWfa; pa.bWatt=bWatt;
  pa.bW1=bW1; pa.bW2=bW2; pa.bW3=bW3; pa.fw1m=fw1m; pa.fw2m=fw2m; pa.fw3m=fw3m;

  hipMemsetAsync(asum_g, 0, (size_t)BN*CC*4, stream);
  hipMemsetAsync(tmax_g, 0, (size_t)BN*CC*4, stream);
  prep_k<<<dim3(64,12), 256, 0, stream>>>(pa);
  featnn_k<<<BN/8, 256, 0, stream>>>(feature, fw1m, fb1, fw2m, fb2, fw3m, fb3, fnnf, fnnb);
  gemm_k<EP_BIAS_F32><<<dim3(4,16), 256, 0, stream>>>(fnnb, bWfa, 512, 1,1,512, bfa, nullptr, fattf, 512, nullptr,nullptr,nullptr);

  for (int b0c = 0; b0c < BN; b0c += CH){
    const int c = (BN - b0c < CH) ? (BN - b0c) : CH;
    const int t = c / 128;                           // 128-batch groups
    conv1_k<<<dim3(t*L1), 256, 0, stream>>>(drug + (size_t)b0c*LD, emb, bt1, db1, bufB);
    gemm_k<EP_RELU_BIAS><<<dim3(2, t*L2), 256, 0, stream>>>(bufB, bt2, 768,  L2, L1, 128, db2, nullptr, bufA, 256, nullptr,nullptr,nullptr);
    gemm_k<EP_RELU_BIAS><<<dim3(4, t*L3), 256, 0, stream>>>(bufA, bt3, 2048, L3, L2, 256, db3, nullptr, bufB, 512, nullptr,nullptr,nullptr);
    gemm_k<EP_RELU_BIAS_FATT><<<dim3(4, t*L3), 256, 0, stream>>>(bufB, bWda, 512, 1,1,512, bda, fattf + (size_t)b0c*CC, bufA, 512, nullptr,nullptr,nullptr);
    gemm_k<EP_ATT><<<dim3(4, t*L3), 256, 0, stream>>>(bufA, bWatt, 512, 1,1,512, batt, nullptr, nullptr, 512,
                                                      bufB, asum_g + (size_t)b0c*CC, tmax_g + (size_t)b0c*CC);
  }

  reduce2_k<<<(BN*CC + 255)/256, 256, 0, stream>>>(asum_g, tmax_g, fnnf, pairb);

  gemm_k<EP_LEAKY_BIAS><<<dim3(8,16), 256, 0, stream>>>(pairb, bW1, 1024, 1,1,1024, b1, nullptr, m1b, 1024, nullptr,nullptr,nullptr);
  gemm_k<EP_LEAKY_BIAS><<<dim3(8,16), 256, 0, stream>>>(m1b,  bW2, 1024, 1,1,1024, b2, nullptr, m2b, 1024, nullptr,nullptr,nullptr);
  gemm_k<EP_LEAKY_BIAS><<<dim3(4,16), 256, 0, stream>>>(m2b,  bW3, 1024, 1,1,1024, b3, nullptr, m3b, 512, nullptr,nullptr,nullptr);
  final_k<<<BN/4, 256, 0, stream>>>(m3b, Wo, bo, out);
}

// Round 7
// 1049.787 us; speedup vs baseline: 1.5305x; 1.0202x over previous
//
#include <hip/hip_runtime.h>
#include <cstdint>
#include <cstddef>

typedef unsigned short ushort_t;
typedef __bf16 bf16x8 __attribute__((ext_vector_type(8)));
typedef float floatx4 __attribute__((ext_vector_type(4)));

#define DEV static __device__ __forceinline__

DEV ushort_t f2bf(float f){
  union { float f; uint32_t u; } v; v.f = f;
  uint32_t u = v.u;
  return (ushort_t)((u + 0x7fffu + ((u >> 16) & 1u)) >> 16);
}
DEV float bf2f(ushort_t h){
  union { uint32_t u; float f; } v; v.u = ((uint32_t)h) << 16; return v.f;
}
DEV float sigmoidf_(float x){ return 1.f / (1.f + __expf(-x)); }

#define AS1 __attribute__((address_space(1)))
#define AS3 __attribute__((address_space(3)))
DEV void gld_lds16(const void* g, void* l){
  __builtin_amdgcn_global_load_lds((const AS1 void*)g, (AS3 void*)l, 16, 0, 0);
}

// XCD-locality swizzle: all x-tiles (n) of one y-tile (m) land on the same XCD.
DEV void swz_xy(int& nx, int& my){
  int gx = gridDim.x, gy = gridDim.y;
  int lin = blockIdx.x + gx * blockIdx.y;
  int full = gy & ~7;
  int region = full * gx;
  if (lin < region){ int q = lin >> 3; nx = q % gx; my = (q / gx) * 8 + (lin & 7); }
  else { int r = lin - region; nx = r % gx; my = full + r / gx; }
}

// ---------------- problem constants ----------------
#define BN 2048
#define LD 100
#define DIM 128
#define L1 97   // after k=4
#define L2 92   // after k=6
#define L3 85   // after k=8
#define CC 512  // C = CONV*4

// ---------------- prep: weight transforms + casts ----------------
struct PrepArgs {
  const float *dw1,*dw2,*dw3,*Wda,*Wfa,*Watt,*W1,*W2,*W3,*fw1,*fw2,*fw3;
  ushort_t *bt1,*bt2,*bt3,*bWda,*bWfa,*bWatt,*bW1,*bW2,*bW3;
  float *fw1m,*fw2m,*fw3m;
};

__global__ void prep_k(PrepArgs a){
  int t0 = blockIdx.x * blockDim.x + threadIdx.x;
  int stride = gridDim.x * blockDim.x;
  switch (blockIdx.y){
  case 0:
    for (int i=t0;i<128*512;i+=stride){ int o=i>>9, rem=i&511, kk=rem>>7, c=rem&127;
      a.bt1[i]=f2bf(a.dw1[o*512 + c*4 + kk]); } break;
  case 1:
    for (int i=t0;i<256*768;i+=stride){ int o=i/768, rem=i-o*768, kk=rem>>7, c=rem&127;
      a.bt2[i]=f2bf(a.dw2[o*768 + c*6 + kk]); } break;
  case 2:
    for (int i=t0;i<512*2048;i+=stride){ int o=i>>11, rem=i&2047, kk=rem>>8, c=rem&255;
      a.bt3[i]=f2bf(a.dw3[o*2048 + c*8 + kk]); } break;
  case 3: for (int i=t0;i<262144;i+=stride) a.bWda[i]=f2bf(a.Wda[i]); break;
  case 4: for (int i=t0;i<262144;i+=stride) a.bWfa[i]=f2bf(a.Wfa[i]); break;
  case 5: for (int i=t0;i<262144;i+=stride) a.bWatt[i]=f2bf(a.Watt[i]); break;
  case 6: for (int i=t0;i<1048576;i+=stride) a.bW1[i]=f2bf(a.W1[i]); break;
  case 7: for (int i=t0;i<1048576;i+=stride) a.bW2[i]=f2bf(a.W2[i]); break;
  case 8: for (int i=t0;i<524288;i+=stride) a.bW3[i]=f2bf(a.W3[i]); break;
  case 9:  for (int i=t0;i<7*128;i+=stride){ int ii=i>>7, o=i&127; a.fw1m[i]=a.fw1[o*21 + ii*3 + 1]; } break;
  case 10: for (int i=t0;i<128*256;i+=stride){ int ii=i>>8, o=i&255; a.fw2m[i]=a.fw2[o*384 + ii*3 + 1]; } break;
  case 11: for (int i=t0;i<256*512;i+=stride){ int ii=i>>9, o=i&511; a.fw3m[i]=a.fw3[o*768 + ii*3 + 1]; } break;
  }
}

// ---------------- feature NN ----------------
__global__ void featnn_k(const float* __restrict__ feature,
                         const float* __restrict__ fw1m, const float* __restrict__ fb1,
                         const float* __restrict__ fw2m, const float* __restrict__ fb2,
                         const float* __restrict__ fw3m, const float* __restrict__ fb3,
                         float* __restrict__ fnnf, ushort_t* __restrict__ fnnb)
{
  __shared__ float fs[8][7];
  __shared__ float h1s[8][128];
  __shared__ float h2s[8][256];
  int b0 = blockIdx.x * 8;
  int tid = threadIdx.x;
  if (tid < 56){ int bb = tid/7, i = tid - bb*7; fs[bb][i] = feature[(b0+bb)*7 + i]; }
  __syncthreads();
  if (tid < 128){
    float acc[8]; float bias = fb1[tid];
    #pragma unroll
    for (int bb=0;bb<8;bb++) acc[bb]=bias;
    for (int i=0;i<7;i++){ float wv = fw1m[i*128+tid];
      #pragma unroll
      for (int bb=0;bb<8;bb++) acc[bb] += wv*fs[bb][i]; }
    #pragma unroll
    for (int bb=0;bb<8;bb++) h1s[bb][tid]=fmaxf(acc[bb],0.f);
  }
  __syncthreads();
  {
    float acc[8]; float bias = fb2[tid];
    #pragma unroll
    for (int bb=0;bb<8;bb++) acc[bb]=bias;
    for (int i=0;i<128;i++){ float wv = fw2m[i*256+tid];
      #pragma unroll
      for (int bb=0;bb<8;bb++) acc[bb] += wv*h1s[bb][i]; }
    #pragma unroll
    for (int bb=0;bb<8;bb++) h2s[bb][tid]=fmaxf(acc[bb],0.f);
  }
  __syncthreads();
  #pragma unroll
  for (int oo=0;oo<2;oo++){
    int o = tid + oo*256;
    float acc[8]; float bias = fb3[o];
    #pragma unroll
    for (int bb=0;bb<8;bb++) acc[bb]=bias;
    for (int i=0;i<256;i++){ float wv = fw3m[i*512+o];
      #pragma unroll
      for (int bb=0;bb<8;bb++) acc[bb] += wv*h2s[bb][i]; }
    #pragma unroll
    for (int bb=0;bb<8;bb++){
      float v = fmaxf(acc[bb],0.f);
      fnnf[(size_t)(b0+bb)*CC + o] = v;
      fnnb[(size_t)(b0+bb)*CC + o] = f2bf(v);
    }
  }
}

// ---------------- conv1 with embedding table resident in LDS ----------------
__global__ __launch_bounds__(256,4) void conv1_k(
    const int* __restrict__ drug,      // chunk-local (batches,100)
    const float* __restrict__ emb,     // (65,128) fp32
    const ushort_t* __restrict__ bt1,  // (128, 512) [o][kk*128+c]
    const float* __restrict__ db1,
    ushort_t* __restrict__ h1)         // (batches*97, 128)
{
  __shared__ __align__(16) ushort_t Bs[128*64];
  __shared__ __align__(16) ushort_t Emb[65*136];
  __shared__ uint8_t Tok[128*4];
  const int tid  = threadIdx.x;
  const int lane = tid & 63;
  const int w    = tid >> 6;
  const int m0   = blockIdx.x * 128;

  for (int idx = tid; idx < 65*128; idx += 256){
    int t2 = idx >> 7, c = idx & 127;
    Emb[t2*136 + c] = f2bf(emb[idx]);
  }
  for (int idx = tid; idx < 128*4; idx += 256){
    int row = idx >> 2, kk = idx & 3;
    int r = m0 + row;
    int b = r / L1, l = r - b*L1;
    Tok[idx] = (uint8_t)drug[b*LD + l + kk];   // l+kk <= 96+3 < 100
  }

  const int chunk = (lane & 7) ^ (lane >> 3);
  const ushort_t* pb[4];
  #pragma unroll
  for (int it=0; it<4; ++it)
    pb[it] = bt1 + (size_t)(it*32 + w*8 + (lane>>3))*512 + (size_t)chunk*8;

  floatx4 acc[4][4];
  #pragma unroll
  for (int i=0;i<4;i++)
    #pragma unroll
    for (int j=0;j<4;j++) acc[i][j] = (floatx4){0.f,0.f,0.f,0.f};

  const int mw = (w & 1) * 64;
  const int nw = (w >> 1) * 64;

  for (int k0=0; k0<512; k0+=64){
    #pragma unroll
    for (int it=0; it<4; ++it){ gld_lds16(pb[it], &Bs[(it*32 + w*8)*64]); pb[it] += 64; }
    __syncthreads();                       // also covers Emb/Tok on first iter
    #pragma unroll
    for (int ks=0; ks<2; ++ks){
      int j  = ks*4 + (lane >> 4);
      int kg = k0 + j*8;
      int kk = kg >> 7, c0 = kg & 127;
      bf16x8 af[4], bfr[4];
      #pragma unroll
      for (int i=0;i<4;i++){
        int rowa = mw + i*16 + (lane & 15);
        int tok = Tok[rowa*4 + kk];
        af[i] = *(const bf16x8*)&Emb[tok*136 + c0];
      }
      #pragma unroll
      for (int j2=0;j2<4;j2++){
        int rowb = nw + j2*16 + (lane & 15);
        bfr[j2] = *(const bf16x8*)&Bs[rowb*64 + ((j ^ (rowb & 7)) << 3)];
      }
      #pragma unroll
      for (int i=0;i<4;i++)
        #pragma unroll
        for (int j2=0;j2<4;j2++)
          acc[i][j2] = __builtin_amdgcn_mfma_f32_16x16x32_bf16(af[i], bfr[j2], acc[i][j2], 0, 0, 0);
    }
    __syncthreads();
  }

  #pragma unroll
  for (int i=0;i<4;i++){
    #pragma unroll
    for (int j2=0;j2<4;j2++){
      #pragma unroll
      for (int r4=0;r4<4;r4++){
        int r = m0 + mw + i*16 + (lane>>4)*4 + r4;
        int n = nw + j2*16 + (lane & 15);
        float v = fmaxf(acc[i][j2][r4] + db1[n], 0.f);
        h1[(size_t)r*128 + n] = f2bf(v);
      }
    }
  }
}

// ---------------- generic 128x128 bf16 MFMA GEMM ----------------
enum { EP_RELU_BIAS=0, EP_RELU_BIAS_FATT=1, EP_ATT=2, EP_LEAKY_BIAS=3, EP_BIAS_F32=4 };

template<int EP>
__global__ __launch_bounds__(256,4) void gemm_k(
    const ushort_t* __restrict__ A, const ushort_t* __restrict__ Bt,
    int K, int LoutA, int LinA, int CinA,
    const float* __restrict__ bias, const float* __restrict__ fatt,
    void* __restrict__ outp, int ldo,
    const ushort_t* __restrict__ dcp, float* __restrict__ asum_g, float* __restrict__ tmax_g)
{
  __shared__ __align__(16) ushort_t As[128*64];
  __shared__ __align__(16) ushort_t Bs[128*64];
  const int tid  = threadIdx.x;
  const int lane = tid & 63;
  const int w    = tid >> 6;
  int nx, my; swz_xy(nx, my);
  const int m0 = my * 128;
  const int n0 = nx * 128;
  const int chunk = (lane & 7) ^ (lane >> 3);

  const ushort_t* pa[4];
  const ushort_t* pb[4];
  #pragma unroll
  for (int it=0; it<4; ++it){
    int row = it*32 + w*8 + (lane>>3);
    int r = m0 + row;
    int bb = r / LoutA;
    int ll = r - bb*LoutA;
    pa[it] = A  + ((size_t)(bb*LinA + ll) * (size_t)CinA + (size_t)chunk*8);
    pb[it] = Bt + ((size_t)(n0+row) * (size_t)K + (size_t)chunk*8);
  }

  floatx4 acc[4][4];
  #pragma unroll
  for (int i=0;i<4;i++)
    #pragma unroll
    for (int j=0;j<4;j++) acc[i][j] = (floatx4){0.f,0.f,0.f,0.f};

  const int mw = (w & 1) * 64;
  const int nw = (w >> 1) * 64;

  for (int k0=0; k0<K; k0+=64){
    #pragma unroll
    for (int it=0; it<4; ++it){
      gld_lds16(pa[it], &As[(it*32 + w*8)*64]);
      gld_lds16(pb[it], &Bs[(it*32 + w*8)*64]);
      pa[it] += 64; pb[it] += 64;
    }
    __syncthreads();
    #pragma unroll
    for (int ks=0; ks<2; ++ks){
      bf16x8 af[4], bfr[4];
      #pragma unroll
      for (int i=0;i<4;i++){
        int rowa = mw + i*16 + (lane & 15);
        int rowb = nw + i*16 + (lane & 15);
        int j = ks*4 + (lane >> 4);
        af[i]  = *(const bf16x8*)&As[rowa*64 + ((j ^ (rowa & 7)) << 3)];
        bfr[i] = *(const bf16x8*)&Bs[rowb*64 + ((j ^ (rowb & 7)) << 3)];
      }
      #pragma unroll
      for (int i=0;i<4;i++)
        #pragma unroll
        for (int j=0;j<4;j++)
          acc[i][j] = __builtin_amdgcn_mfma_f32_16x16x32_bf16(af[i], bfr[j], acc[i][j], 0, 0, 0);
    }
    __syncthreads();
  }

  if constexpr (EP == EP_ATT){
    __shared__ float red_sum[3*128];
    __shared__ int   red_max[3*128];
    const int bfirst = m0 / L3;
    for (int t2 = tid; t2 < 3*128; t2 += 256){ red_sum[t2] = 0.f; red_max[t2] = 0; }
    __syncthreads();
    const int segA = (m0 + mw) / L3 - bfirst;
    #pragma unroll
    for (int j=0;j<4;j++){
      int col = nw + j*16 + (lane & 15);
      int n = n0 + col;
      float bi = bias[n];
      float s0 = 0.f, s1 = 0.f, x0 = 0.f, x1 = 0.f;
      #pragma unroll
      for (int i=0;i<4;i++){
        #pragma unroll
        for (int r4=0;r4<4;r4++){
          int m = m0 + mw + i*16 + (lane>>4)*4 + r4;
          float Av = acc[i][j][r4] + bi;
          float dcv = bf2f(dcp[(size_t)m*CC + n]);
          float tv = dcv * (0.5f + sigmoidf_(Av));
          if ((m / L3 - bfirst) == segA){ s0 += Av; x0 = fmaxf(x0, tv); }
          else                          { s1 += Av; x1 = fmaxf(x1, tv); }
        }
      }
      atomicAdd(&red_sum[segA*128 + col], s0);
      atomicMax(&red_max[segA*128 + col], __float_as_int(x0));
      if (segA + 1 < 3){
        atomicAdd(&red_sum[(segA+1)*128 + col], s1);
        atomicMax(&red_max[(segA+1)*128 + col], __float_as_int(x1));
      }
    }
    __syncthreads();
    for (int t2 = tid; t2 < 3*128; t2 += 256){
      int seg = t2 >> 7, col = t2 & 127;
      int b = bfirst + seg;
      if (b * L3 < m0 + 128){
        atomicAdd(asum_g + (size_t)b*CC + n0 + col, red_sum[t2]);
        atomicMax((int*)tmax_g + (size_t)b*CC + n0 + col, red_max[t2]);
      }
    }
    return;
  }

  float* outf = (float*)outp;
  ushort_t* outh = (ushort_t*)outp;
  #pragma unroll
  for (int i=0;i<4;i++){
    #pragma unroll
    for (int j=0;j<4;j++){
      #pragma unroll
      for (int r4=0;r4<4;r4++){
        int m = m0 + mw + i*16 + (lane>>4)*4 + r4;
        int n = n0 + nw + j*16 + (lane & 15);
        float v = acc[i][j][r4] + bias[n];
        if constexpr (EP == EP_RELU_BIAS)       v = fmaxf(v, 0.f);
        else if constexpr (EP == EP_RELU_BIAS_FATT){ v += fatt[(m / L3)*CC + n]; v = fmaxf(v, 0.f); }
        else if constexpr (EP == EP_LEAKY_BIAS) v = v > 0.f ? v : 0.01f*v;
        if constexpr (EP == EP_BIAS_F32) outf[(size_t)m*ldo + n] = v;
        else                             outh[(size_t)m*ldo + n] = f2bf(v);
      }
    }
  }
}

// ---------------- finish pooling ----------------
__global__ void reduce2_k(const float* __restrict__ asum, const float* __restrict__ tmax,
                          const float* __restrict__ fnnf, ushort_t* __restrict__ pair)
{
  int g = blockIdx.x * blockDim.x + threadIdx.x;
  if (g >= BN * CC) return;
  int b = g >> 9, c = g & 511;
  pair[(size_t)b*1024 + c] = f2bf(tmax[g]);
  float fv = fnnf[g] * (0.5f + sigmoidf_(asum[g] * (1.f/(float)L3)));
  pair[(size_t)b*1024 + 512 + c] = f2bf(fv);
}

// ---------------- final dot ----------------
__global__ void final_k(const ushort_t* __restrict__ h3, const float* __restrict__ Wo,
                        const float* __restrict__ bo, float* __restrict__ out)
{
  int b = blockIdx.x*4 + (threadIdx.x >> 6);
  int lane = threadIdx.x & 63;
  float acc = 0.f;
  for (int i=lane; i<512; i+=64) acc += bf2f(h3[(size_t)b*512 + i]) * Wo[i];
  #pragma unroll
  for (int off=32; off; off>>=1) acc += __shfl_down(acc, off);
  if (lane == 0) out[b] = acc + bo[0];
}

// ---------------- host ----------------
extern "C" void kernel_launch(void* const* d_in, const int* in_sizes, int n_in,
                              void* d_out, int out_size, void* d_ws, size_t ws_size,
                              hipStream_t stream)
{
  (void)in_sizes; (void)n_in; (void)out_size;
  const int*   drug    = (const int*)  d_in[0];
  const float* feature = (const float*)d_in[1];
  const float* emb     = (const float*)d_in[2];
  const float* dw1 = (const float*)d_in[3];  const float* db1 = (const float*)d_in[4];
  const float* dw2 = (const float*)d_in[5];  const float* db2 = (const float*)d_in[6];
  const float* dw3 = (const float*)d_in[7];  const float* db3 = (const float*)d_in[8];
  const float* fw1 = (const float*)d_in[9];  const float* fb1 = (const float*)d_in[10];
  const float* fw2 = (const float*)d_in[11]; const float* fb2 = (const float*)d_in[12];
  const float* fw3 = (const float*)d_in[13]; const float* fb3 = (const float*)d_in[14];
  const float* Wda = (const float*)d_in[15]; const float* bda = (const float*)d_in[16];
  const float* Wfa = (const float*)d_in[17]; const float* bfa = (const float*)d_in[18];
  const float* Watt= (const float*)d_in[19]; const float* batt= (const float*)d_in[20];
  const float* W1  = (const float*)d_in[21]; const float* b1  = (const float*)d_in[22];
  const float* W2  = (const float*)d_in[23]; const float* b2  = (const float*)d_in[24];
  const float* W3  = (const float*)d_in[25]; const float* b3  = (const float*)d_in[26];
  const float* Wo  = (const float*)d_in[27]; const float* bo  = (const float*)d_in[28];
  float* out = (float*)d_out;

  size_t off = 0; char* base = (char*)d_ws;
  auto alloc = [&](size_t bytes)->char*{
    off = (off + 255) & ~(size_t)255; char* p = base + off; off += bytes; return p;
  };
  ushort_t* bt1  = (ushort_t*)alloc(128*512*2);
  ushort_t* bt2  = (ushort_t*)alloc(256*768*2);
  ushort_t* bt3  = (ushort_t*)alloc((size_t)512*2048*2);
  ushort_t* bWda = (ushort_t*)alloc(262144*2);
  ushort_t* bWfa = (ushort_t*)alloc(262144*2);
  ushort_t* bWatt= (ushort_t*)alloc(262144*2);
  ushort_t* bW1  = (ushort_t*)alloc((size_t)1048576*2);
  ushort_t* bW2  = (ushort_t*)alloc((size_t)1048576*2);
  ushort_t* bW3  = (ushort_t*)alloc((size_t)524288*2);
  float* fw1m = (float*)alloc(7*128*4);
  float* fw2m = (float*)alloc(128*256*4);
  float* fw3m = (float*)alloc(256*512*4);
  float* fnnf = (float*)alloc((size_t)BN*CC*4);
  ushort_t* fnnb = (ushort_t*)alloc((size_t)BN*CC*2);
  float* fattf = (float*)alloc((size_t)BN*CC*4);
  float* asum_g = (float*)alloc((size_t)BN*CC*4);
  float* tmax_g = (float*)alloc((size_t)BN*CC*4);
  ushort_t* pairb = (ushort_t*)alloc((size_t)BN*1024*2);
  ushort_t* m1b = (ushort_t*)alloc((size_t)BN*1024*2);
  ushort_t* m2b = (ushort_t*)alloc((size_t)BN*1024*2);
  ushort_t* m3b = (ushort_t*)alloc((size_t)BN*512*2);

  // Ping-pong chunk buffers. Per-batch per buffer = 85*512*2 = 87040 bytes.
  const size_t PER_BUF = 87040, PER_CHUNK = 2*PER_BUF;
  size_t avail = (ws_size > off + 4096) ? (ws_size - off - 4096) : 0;
  int CHmax = (int)(avail / PER_CHUNK);
  if (CHmax > BN) CHmax = BN;
  CHmax = (CHmax / 128) * 128;
  if (CHmax < 128) CHmax = 128;
  // equal chunks: smallest NC covering BN, then CH = ceil(BN/NC) rounded up to 128
  int NC = (BN + CHmax - 1) / CHmax;
  int CH = ((BN / NC + 127) / 128) * 128;
  if (CH > CHmax) CH = CHmax;
  char* chunkbase = alloc((size_t)CH*PER_CHUNK);
  ushort_t* bufA = (ushort_t*)chunkbase;
  ushort_t* bufB = (ushort_t*)(chunkbase + (size_t)CH*PER_BUF);

  PrepArgs pa;
  pa.dw1=dw1; pa.dw2=dw2; pa.dw3=dw3; pa.Wda=Wda; pa.Wfa=Wfa; pa.Watt=Watt;
  pa.W1=W1; pa.W2=W2; pa.W3=W3; pa.fw1=fw1; pa.fw2=fw2; pa.fw3=fw3;
  pa.bt1=bt1; pa.bt2=bt2; pa.bt3=bt3; pa.bWda=bWda; pa.bWfa=bWfa; pa.bWatt=bWatt;
  pa.bW1=bW1; pa.bW2=bW2; pa.bW3=bW3; pa.fw1m=fw1m; pa.fw2m=fw2m; pa.fw3m=fw3m;

  hipMemsetAsync(asum_g, 0, (size_t)BN*CC*4, stream);
  hipMemsetAsync(tmax_g, 0, (size_t)BN*CC*4, stream);
  prep_k<<<dim3(64,12), 256, 0, stream>>>(pa);
  featnn_k<<<BN/8, 256, 0, stream>>>(feature, fw1m, fb1, fw2m, fb2, fw3m, fb3, fnnf, fnnb);
  gemm_k<EP_BIAS_F32><<<dim3(4,16), 256, 0, stream>>>(fnnb, bWfa, 512, 1,1,512, bfa, nullptr, fattf, 512, nullptr,nullptr,nullptr);

  for (int b0c = 0; b0c < BN; b0c += CH){
    const int c = (BN - b0c < CH) ? (BN - b0c) : CH;
    const int t = c / 128;                           // 128-batch groups
    conv1_k<<<dim3(t*L1), 256, 0, stream>>>(drug + (size_t)b0c*LD, emb, bt1, db1, bufB);
    gemm_k<EP_RELU_BIAS><<<dim3(2, t*L2), 256, 0, stream>>>(bufB, bt2, 768,  L2, L1, 128, db2, nullptr, bufA, 256, nullptr,nullptr,nullptr);
    gemm_k<EP_RELU_BIAS><<<dim3(4, t*L3), 256, 0, stream>>>(bufA, bt3, 2048, L3, L2, 256, db3, nullptr, bufB, 512, nullptr,nullptr,nullptr);
    gemm_k<EP_RELU_BIAS_FATT><<<dim3(4, t*L3), 256, 0, stream>>>(bufB, bWda, 512, 1,1,512, bda, fattf + (size_t)b0c*CC, bufA, 512, nullptr,nullptr,nullptr);
    gemm_k<EP_ATT><<<dim3(4, t*L3), 256, 0, stream>>>(bufA, bWatt, 512, 1,1,512, batt, nullptr, nullptr, 512,
                                                      bufB, asum_g + (size_t)b0c*CC, tmax_g + (size_t)b0c*CC);
  }

  reduce2_k<<<(BN*CC + 255)/256, 256, 0, stream>>>(asum_g, tmax_g, fnnf, pairb);

  gemm_k<EP_LEAKY_BIAS><<<dim3(8,16), 256, 0, stream>>>(pairb, bW1, 1024, 1,1,1024, b1, nullptr, m1b, 1024, nullptr,nullptr,nullptr);
  gemm_k<EP_LEAKY_BIAS><<<dim3(8,16), 256, 0, stream>>>(m1b,  bW2, 1024, 1,1,1024, b2, nullptr, m2b, 1024, nullptr,nullptr,nullptr);
  gemm_k<EP_LEAKY_BIAS><<<dim3(4,16), 256, 0, stream>>>(m2b,  bW3, 1024, 1,1,1024, b3, nullptr, m3b, 512, nullptr,nullptr,nullptr);
  final_k<<<BN/4, 256, 0, stream>>>(m3b, Wo, bo, out);
}